// Round 1
// baseline (545.417 us; speedup 1.0000x reference)
//
#include <hip/hip_runtime.h>

#define N_NODES 50000
#define N_EDGES 800000
#define D 128

// ---------------- CSR build ----------------

__global__ void k_deg(const int* __restrict__ dst, int* __restrict__ deg) {
    int e = blockIdx.x * blockDim.x + threadIdx.x;
    if (e < N_EDGES) atomicAdd(&deg[dst[e]], 1);
}

__global__ void k_scan1(const int* __restrict__ deg, int* __restrict__ rs,
                        int* __restrict__ bsum) {
    __shared__ int s[1024];
    int tid = threadIdx.x;
    int i = blockIdx.x * 1024 + tid;
    int v = (i < N_NODES) ? deg[i] : 0;
    s[tid] = v;
    __syncthreads();
    for (int off = 1; off < 1024; off <<= 1) {
        int t = (tid >= off) ? s[tid - off] : 0;
        __syncthreads();
        s[tid] += t;
        __syncthreads();
    }
    if (i < N_NODES) rs[i] = s[tid] - v;          // block-local exclusive
    if (tid == 1023) bsum[blockIdx.x] = s[1023];  // block total
}

__global__ void k_scan2(int* __restrict__ bsum, int nb) {
    if (threadIdx.x == 0 && blockIdx.x == 0) {
        int running = 0;
        for (int b = 0; b < nb; ++b) {
            int t = bsum[b];
            bsum[b] = running;
            running += t;
        }
    }
}

__global__ void k_scan3(int* __restrict__ rs, const int* __restrict__ bsum) {
    int i = blockIdx.x * blockDim.x + threadIdx.x;
    if (i < N_NODES) rs[i] += bsum[i >> 10];
    if (i == 0) rs[N_NODES] = N_EDGES;
}

__global__ void k_fill(const int* __restrict__ src, const int* __restrict__ dst,
                       const int* __restrict__ rs, int* __restrict__ cur,
                       int* __restrict__ col) {
    int e = blockIdx.x * blockDim.x + threadIdx.x;
    if (e < N_EDGES) {
        int d = dst[e];
        int p = atomicAdd(&cur[d], 1);
        col[rs[d] + p] = src[e];
    }
}

// ---------------- mean aggregation (no atomics, CSR gather) ----------------

__global__ void k_agg(const float* __restrict__ h, const int* __restrict__ rs,
                      const int* __restrict__ col, float* __restrict__ mean) {
    int node = blockIdx.x;
    int d = threadIdx.x;  // 128 threads
    int j0 = rs[node], j1 = rs[node + 1];
    float acc = 0.f;
    for (int j = j0; j < j1; ++j) {
        int c = col[j];  // wave-uniform -> scalar load
        acc += h[c * D + d];
    }
    int cnt = j1 - j0;
    float scale = 1.0f / (float)(cnt > 0 ? cnt : 1);
    mean[node * D + d] = acc * scale;
}

// ---------------- fused dual GEMM: out = mean@Wn + h@Wr + b (+relu) -------
// A = [mean | h]  (K=256), W = [Wn ; Wr] (256x128), 64-row tile per block.

template <int ACT>
__global__ __launch_bounds__(256) void k_gemm(
    const float* __restrict__ mean, const float* __restrict__ h,
    const float* __restrict__ wn, const float* __restrict__ wr,
    const float* __restrict__ bias, float* __restrict__ out) {
    __shared__ float As[64][64];    // [k][m]  16 KB
    __shared__ float Ws[64][128];   // [k][c]  32 KB
    const int t = threadIdx.x;
    const int rowbase = blockIdx.x * 64;
    const int c = (t & 31) * 4;     // output col group
    const int m0 = (t >> 5) * 8;    // output row group

    float acc[8][4] = {};

    for (int kc = 0; kc < 4; ++kc) {
        const float* Asrc = (kc < 2) ? mean : h;
        const float* Wsrc = (kc < 2) ? wn : wr;
        const int k0 = (kc & 1) * 64;

        __syncthreads();  // previous compute done before overwrite
        // A tile: 64 rows x 64 k, loaded coalesced, stored transposed [k][m]
        #pragma unroll
        for (int j = 0; j < 4; ++j) {
            int f = t * 4 + j;
            int row = f >> 4;
            int kq = (f & 15) * 4;
            int grow = rowbase + row;
            float4 v = make_float4(0.f, 0.f, 0.f, 0.f);
            if (grow < N_NODES)
                v = *reinterpret_cast<const float4*>(&Asrc[grow * D + k0 + kq]);
            As[kq + 0][row] = v.x;
            As[kq + 1][row] = v.y;
            As[kq + 2][row] = v.z;
            As[kq + 3][row] = v.w;
        }
        // W tile: 64 k x 128 c
        #pragma unroll
        for (int j = 0; j < 8; ++j) {
            int f = j * 256 + t;
            int k = f >> 5;
            int c4 = (f & 31) * 4;
            *reinterpret_cast<float4*>(&Ws[k][c4]) =
                *reinterpret_cast<const float4*>(&Wsrc[(k0 + k) * D + c4]);
        }
        __syncthreads();

        #pragma unroll
        for (int k = 0; k < 64; ++k) {
            float4 w4 = *reinterpret_cast<const float4*>(&Ws[k][c]);
            float4 a0 = *reinterpret_cast<const float4*>(&As[k][m0]);
            float4 a1 = *reinterpret_cast<const float4*>(&As[k][m0 + 4]);
            float a8[8] = {a0.x, a0.y, a0.z, a0.w, a1.x, a1.y, a1.z, a1.w};
            #pragma unroll
            for (int m = 0; m < 8; ++m) {
                acc[m][0] += a8[m] * w4.x;
                acc[m][1] += a8[m] * w4.y;
                acc[m][2] += a8[m] * w4.z;
                acc[m][3] += a8[m] * w4.w;
            }
        }
    }

    float4 bv = *reinterpret_cast<const float4*>(&bias[c]);
    #pragma unroll
    for (int m = 0; m < 8; ++m) {
        int grow = rowbase + m0 + m;
        if (grow < N_NODES) {
            float4 o;
            o.x = acc[m][0] + bv.x;
            o.y = acc[m][1] + bv.y;
            o.z = acc[m][2] + bv.z;
            o.w = acc[m][3] + bv.w;
            if (ACT) {
                o.x = o.x > 0.f ? o.x : 0.f;
                o.y = o.y > 0.f ? o.y : 0.f;
                o.z = o.z > 0.f ? o.z : 0.f;
                o.w = o.w > 0.f ? o.w : 0.f;
            }
            *reinterpret_cast<float4*>(&out[grow * D + c]) = o;
        }
    }
}

// ---------------- classifier: out[i] = h[i] . w_cls + b ----------------

__global__ void k_cls(const float* __restrict__ h, const float* __restrict__ wc,
                      const float* __restrict__ bc, float* __restrict__ out) {
    int node = blockIdx.x * 4 + (threadIdx.x >> 6);
    int l = threadIdx.x & 63;
    if (node >= N_NODES) return;
    float p = h[node * D + l] * wc[l] + h[node * D + 64 + l] * wc[64 + l];
    #pragma unroll
    for (int off = 32; off > 0; off >>= 1) p += __shfl_down(p, off, 64);
    if (l == 0) out[node] = p + bc[0];
}

// ---------------- launch ----------------

extern "C" void kernel_launch(void* const* d_in, const int* in_sizes, int n_in,
                              void* d_out, int out_size, void* d_ws,
                              size_t ws_size, hipStream_t stream) {
    const float* x = (const float*)d_in[0];
    const int* ei = (const int*)d_in[1];
    const int* src = ei;
    const int* dst = ei + N_EDGES;
    const float* wn[3] = {(const float*)d_in[2], (const float*)d_in[5],
                          (const float*)d_in[8]};
    const float* wr[3] = {(const float*)d_in[3], (const float*)d_in[6],
                          (const float*)d_in[9]};
    const float* bs[3] = {(const float*)d_in[4], (const float*)d_in[7],
                          (const float*)d_in[10]};
    const float* wc = (const float*)d_in[11];
    const float* bc = (const float*)d_in[12];
    float* out = (float*)d_out;

    char* ws = (char*)d_ws;
    size_t off = 0;
    auto alloc = [&](size_t bytes) -> void* {
        void* p = (void*)(ws + off);
        off += (bytes + 255) & ~(size_t)255;
        return p;
    };
    int* deg = (int*)alloc(N_NODES * 4);
    int* rs = (int*)alloc((N_NODES + 1) * 4);
    int* cur = (int*)alloc(N_NODES * 4);
    int* bsum = (int*)alloc(64 * 4);
    int* col = (int*)alloc(N_EDGES * 4);
    float* mean = (float*)alloc((size_t)N_NODES * D * 4);
    float* h0 = (float*)alloc((size_t)N_NODES * D * 4);

    hipMemsetAsync(deg, 0, N_NODES * 4, stream);
    hipMemsetAsync(cur, 0, N_NODES * 4, stream);

    int nb = (N_NODES + 1023) / 1024;
    k_deg<<<(N_EDGES + 255) / 256, 256, 0, stream>>>(dst, deg);
    k_scan1<<<nb, 1024, 0, stream>>>(deg, rs, bsum);
    k_scan2<<<1, 64, 0, stream>>>(bsum, nb);
    k_scan3<<<(N_NODES + 255) / 256, 256, 0, stream>>>(rs, bsum);
    k_fill<<<(N_EDGES + 255) / 256, 256, 0, stream>>>(src, dst, rs, cur, col);

    int gblk = (N_NODES + 63) / 64;
    // layer 0: x -> h0 (relu)
    k_agg<<<N_NODES, D, 0, stream>>>(x, rs, col, mean);
    k_gemm<1><<<gblk, 256, 0, stream>>>(mean, x, wn[0], wr[0], bs[0], h0);
    // layer 1: h0 -> h0 (relu, in-place: rows are block-exclusive)
    k_agg<<<N_NODES, D, 0, stream>>>(h0, rs, col, mean);
    k_gemm<1><<<gblk, 256, 0, stream>>>(mean, h0, wn[1], wr[1], bs[1], h0);
    // layer 2: h0 -> h0 (no relu)
    k_agg<<<N_NODES, D, 0, stream>>>(h0, rs, col, mean);
    k_gemm<0><<<gblk, 256, 0, stream>>>(mean, h0, wn[2], wr[2], bs[2], h0);

    k_cls<<<(N_NODES + 3) / 4, 256, 0, stream>>>(h0, wc, bc, out);
}

// Round 2
// 254.921 us; speedup vs baseline: 2.1396x; 2.1396x over previous
//
#include <hip/hip_runtime.h>

#define N_NODES 50000
#define N_EDGES 800000
#define D 128
#define NGROUPS 3125  // N_NODES / 16

typedef __attribute__((ext_vector_type(8))) short short8;
typedef __attribute__((ext_vector_type(4))) float f32x4;

__device__ __forceinline__ float bits2f(unsigned int u) {
    union { unsigned int u; float f; } c; c.u = u; return c.f;
}
__device__ __forceinline__ unsigned short f2b(float f) {
    union { float f; unsigned int u; } c; c.f = f;
    unsigned int r = c.u + 0x7fffu + ((c.u >> 16) & 1u);
    return (unsigned short)(r >> 16);
}

// ---------------- CSR build ----------------

__global__ void k_deg(const int* __restrict__ dst, int* __restrict__ deg) {
    int e = blockIdx.x * blockDim.x + threadIdx.x;
    if (e < N_EDGES) atomicAdd(&deg[dst[e]], 1);
}

__global__ void k_scan1(const int* __restrict__ deg, int* __restrict__ rs,
                        int* __restrict__ bsum) {
    __shared__ int s[1024];
    int tid = threadIdx.x;
    int i = blockIdx.x * 1024 + tid;
    int v = (i < N_NODES) ? deg[i] : 0;
    s[tid] = v;
    __syncthreads();
    for (int off = 1; off < 1024; off <<= 1) {
        int t = (tid >= off) ? s[tid - off] : 0;
        __syncthreads();
        s[tid] += t;
        __syncthreads();
    }
    if (i < N_NODES) rs[i] = s[tid] - v;
    if (tid == 1023) bsum[blockIdx.x] = s[1023];
}

__global__ void k_scan2(int* __restrict__ bsum, int nb) {
    if (threadIdx.x == 0 && blockIdx.x == 0) {
        int running = 0;
        for (int b = 0; b < nb; ++b) {
            int t = bsum[b];
            bsum[b] = running;
            running += t;
        }
    }
}

__global__ void k_scan3(int* __restrict__ rs, const int* __restrict__ bsum) {
    int i = blockIdx.x * blockDim.x + threadIdx.x;
    if (i < N_NODES) rs[i] += bsum[i >> 10];
    if (i == 0) rs[N_NODES] = N_EDGES;
}

__global__ void k_fill(const int* __restrict__ src, const int* __restrict__ dst,
                       const int* __restrict__ rs, int* __restrict__ cur,
                       int* __restrict__ col) {
    int e = blockIdx.x * blockDim.x + threadIdx.x;
    if (e < N_EDGES) {
        int d = dst[e];
        int p = atomicAdd(&cur[d], 1);
        col[rs[d] + p] = src[e];
    }
}

// ---------------- f32 -> bf16 cast ----------------

__global__ void k_cast(const float* __restrict__ x, unsigned short* __restrict__ xb) {
    int i = blockIdx.x * blockDim.x + threadIdx.x;  // one float4 each
    if (i >= (N_NODES * D) / 4) return;
    float4 v = reinterpret_cast<const float4*>(x)[i];
    ushort4 o;
    o.x = f2b(v.x); o.y = f2b(v.y); o.z = f2b(v.z); o.w = f2b(v.w);
    reinterpret_cast<ushort4*>(xb)[i] = o;
}

// ---------------- pack weights into MFMA B-fragment order ----------------
// Bp[layer][kstep][cf][lane][i] = W[kstep*32 + 8*(lane>>4) + i][cf*16 + (lane&15)]
// kstep<4 -> w_nbr, else w_root (k offset -128).

__global__ void k_packw(const float* __restrict__ wn0, const float* __restrict__ wr0,
                        const float* __restrict__ wn1, const float* __restrict__ wr1,
                        const float* __restrict__ wn2, const float* __restrict__ wr2,
                        unsigned short* __restrict__ Bp) {
    int t = blockIdx.x * blockDim.x + threadIdx.x;
    if (t >= 3 * 8 * 8 * 64) return;
    int layer = t >> 12;
    int rem = t & 4095;
    int kstep = rem >> 9;
    int cf = (rem >> 6) & 7;
    int lane = t & 63;
    const float* wns[3] = {wn0, wn1, wn2};
    const float* wrs[3] = {wr0, wr1, wr2};
    int kb = kstep * 32 + (lane >> 4) * 8;
    int colv = cf * 16 + (lane & 15);
    const float* W = (kstep < 4) ? wns[layer] : wrs[layer];
    int koff = (kstep < 4) ? kb : kb - 128;
    unsigned short* dstp = Bp + (((layer * 64 + kstep * 8 + cf) * 64 + lane) << 3);
    #pragma unroll
    for (int i = 0; i < 8; ++i) dstp[i] = f2b(W[(koff + i) * D + colv]);
}

// ---------------- mean aggregation: bf16 gather, 4 rows in flight/wave ----

__global__ __launch_bounds__(256) void k_aggb(const unsigned short* __restrict__ h,
                                              const int* __restrict__ rs,
                                              const int* __restrict__ col,
                                              unsigned short* __restrict__ mean) {
    int lane = threadIdx.x & 63;
    int node = blockIdx.x * 4 + (threadIdx.x >> 6);
    if (node >= N_NODES) return;
    int j0 = rs[node], j1 = rs[node + 1];
    int q = lane >> 4;            // which of 4 concurrent neighbors
    int d8 = (lane & 15) * 8;     // 8 bf16 (16B) per lane
    float acc[8] = {0.f, 0.f, 0.f, 0.f, 0.f, 0.f, 0.f, 0.f};
    for (int j = j0 + q; j < j1; j += 4) {
        int c = col[j];
        uint4 v = *reinterpret_cast<const uint4*>(h + c * D + d8);
        acc[0] += bits2f(v.x << 16); acc[1] += bits2f(v.x & 0xffff0000u);
        acc[2] += bits2f(v.y << 16); acc[3] += bits2f(v.y & 0xffff0000u);
        acc[4] += bits2f(v.z << 16); acc[5] += bits2f(v.z & 0xffff0000u);
        acc[6] += bits2f(v.w << 16); acc[7] += bits2f(v.w & 0xffff0000u);
    }
    #pragma unroll
    for (int i = 0; i < 8; ++i) {
        acc[i] += __shfl_xor(acc[i], 16, 64);
        acc[i] += __shfl_xor(acc[i], 32, 64);
    }
    if (lane < 16) {
        int cnt = j1 - j0;
        float s = 1.0f / (float)(cnt > 0 ? cnt : 1);
        uint4 o;
        o.x = (unsigned int)f2b(acc[0] * s) | ((unsigned int)f2b(acc[1] * s) << 16);
        o.y = (unsigned int)f2b(acc[2] * s) | ((unsigned int)f2b(acc[3] * s) << 16);
        o.z = (unsigned int)f2b(acc[4] * s) | ((unsigned int)f2b(acc[5] * s) << 16);
        o.w = (unsigned int)f2b(acc[6] * s) | ((unsigned int)f2b(acc[7] * s) << 16);
        *reinterpret_cast<uint4*>(mean + node * D + d8) = o;
    }
}

// ---------------- MFMA GEMM: out = [mean|h] @ [Wn;Wr] + b (+relu / +cls) --
// One wave per 16-row group; full N=128 (8 col-frags); K=256 in 8 steps.
// A-frag: lane holds A[row0+(lane&15)][kstep*32 + 8*(lane>>4) .. +7].
// C/D: col = lane&15 (within frag), row = row0 + (lane>>4)*4 + i.

template <int ACT, int CLS>
__global__ __launch_bounds__(256) void k_gemm(
    const unsigned short* __restrict__ Amean, const unsigned short* __restrict__ Ah,
    const unsigned short* __restrict__ Bp, const float* __restrict__ bias,
    unsigned short* __restrict__ outh, const float* __restrict__ wc,
    const float* __restrict__ bc, float* __restrict__ outf) {
    int lane = threadIdx.x & 63;
    int group = blockIdx.x * 4 + (threadIdx.x >> 6);
    if (group >= NGROUPS) return;
    int row0 = group * 16;
    int arow = row0 + (lane & 15);
    int klane = (lane >> 4) * 8;

    f32x4 acc[8];
    #pragma unroll
    for (int i = 0; i < 8; ++i) acc[i] = (f32x4)0.0f;

    const short8* bpv = reinterpret_cast<const short8*>(Bp);
    #pragma unroll
    for (int kstep = 0; kstep < 8; ++kstep) {
        const unsigned short* Asrc = (kstep < 4) ? Amean : Ah;
        int kk = (kstep & 3) * 32 + klane;
        short8 a = *reinterpret_cast<const short8*>(Asrc + arow * D + kk);
        #pragma unroll
        for (int cf = 0; cf < 8; ++cf) {
            short8 b = bpv[(kstep * 8 + cf) * 64 + lane];
            acc[cf] = __builtin_amdgcn_mfma_f32_16x16x32_bf16(a, b, acc[cf], 0, 0, 0);
        }
    }

    int rbase = row0 + (lane >> 4) * 4;
    if (CLS) {
        float p0 = 0.f, p1 = 0.f, p2 = 0.f, p3 = 0.f;
        #pragma unroll
        for (int cf = 0; cf < 8; ++cf) {
            int bcol = cf * 16 + (lane & 15);
            float bv = bias[bcol];
            float wcv = wc[bcol];
            p0 += (acc[cf][0] + bv) * wcv;
            p1 += (acc[cf][1] + bv) * wcv;
            p2 += (acc[cf][2] + bv) * wcv;
            p3 += (acc[cf][3] + bv) * wcv;
        }
        #pragma unroll
        for (int m = 1; m < 16; m <<= 1) {
            p0 += __shfl_xor(p0, m, 64);
            p1 += __shfl_xor(p1, m, 64);
            p2 += __shfl_xor(p2, m, 64);
            p3 += __shfl_xor(p3, m, 64);
        }
        if ((lane & 15) == 0) {
            float bcv = bc[0];
            outf[rbase + 0] = p0 + bcv;
            outf[rbase + 1] = p1 + bcv;
            outf[rbase + 2] = p2 + bcv;
            outf[rbase + 3] = p3 + bcv;
        }
    } else {
        #pragma unroll
        for (int cf = 0; cf < 8; ++cf) {
            int bcol = cf * 16 + (lane & 15);
            float bv = bias[bcol];
            #pragma unroll
            for (int i = 0; i < 4; ++i) {
                float v = acc[cf][i] + bv;
                if (ACT) v = fmaxf(v, 0.f);
                outh[(rbase + i) * D + bcol] = f2b(v);
            }
        }
    }
}

// ---------------- launch ----------------

extern "C" void kernel_launch(void* const* d_in, const int* in_sizes, int n_in,
                              void* d_out, int out_size, void* d_ws,
                              size_t ws_size, hipStream_t stream) {
    const float* x = (const float*)d_in[0];
    const int* ei = (const int*)d_in[1];
    const int* src = ei;
    const int* dst = ei + N_EDGES;
    const float* wn[3] = {(const float*)d_in[2], (const float*)d_in[5],
                          (const float*)d_in[8]};
    const float* wr[3] = {(const float*)d_in[3], (const float*)d_in[6],
                          (const float*)d_in[9]};
    const float* bs[3] = {(const float*)d_in[4], (const float*)d_in[7],
                          (const float*)d_in[10]};
    const float* wc = (const float*)d_in[11];
    const float* bc = (const float*)d_in[12];
    float* out = (float*)d_out;

    char* ws = (char*)d_ws;
    size_t off = 0;
    auto alloc = [&](size_t bytes) -> void* {
        void* p = (void*)(ws + off);
        off += (bytes + 255) & ~(size_t)255;
        return p;
    };
    int* deg = (int*)alloc(N_NODES * 4);
    int* rs = (int*)alloc((N_NODES + 1) * 4);
    int* cur = (int*)alloc(N_NODES * 4);
    int* bsum = (int*)alloc(64 * 4);
    int* col = (int*)alloc(N_EDGES * 4);
    unsigned short* xbf = (unsigned short*)alloc((size_t)N_NODES * D * 2);
    unsigned short* hbf = (unsigned short*)alloc((size_t)N_NODES * D * 2);
    unsigned short* meanbf = (unsigned short*)alloc((size_t)N_NODES * D * 2);
    unsigned short* Bp = (unsigned short*)alloc(3 * 256 * 128 * 2);

    hipMemsetAsync(deg, 0, N_NODES * 4, stream);
    hipMemsetAsync(cur, 0, N_NODES * 4, stream);

    int nb = (N_NODES + 1023) / 1024;
    k_deg<<<(N_EDGES + 255) / 256, 256, 0, stream>>>(dst, deg);
    k_scan1<<<nb, 1024, 0, stream>>>(deg, rs, bsum);
    k_scan2<<<1, 64, 0, stream>>>(bsum, nb);
    k_scan3<<<(N_NODES + 255) / 256, 256, 0, stream>>>(rs, bsum);
    k_fill<<<(N_EDGES + 255) / 256, 256, 0, stream>>>(src, dst, rs, cur, col);

    k_cast<<<(N_NODES * D / 4 + 255) / 256, 256, 0, stream>>>(x, xbf);
    k_packw<<<48, 256, 0, stream>>>(wn[0], wr[0], wn[1], wr[1], wn[2], wr[2], Bp);

    const int agg_grid = (N_NODES + 3) / 4;
    const int gemm_grid = (NGROUPS + 3) / 4;
    unsigned short* Bp0 = Bp;
    unsigned short* Bp1 = Bp + 256 * 128;
    unsigned short* Bp2 = Bp + 2 * 256 * 128;

    // layer 0: x -> hbf (relu)
    k_aggb<<<agg_grid, 256, 0, stream>>>(xbf, rs, col, meanbf);
    k_gemm<1, 0><<<gemm_grid, 256, 0, stream>>>(meanbf, xbf, Bp0, bs[0], hbf,
                                                nullptr, nullptr, nullptr);
    // layer 1: hbf -> hbf (relu, in-place: rows block-exclusive)
    k_aggb<<<agg_grid, 256, 0, stream>>>(hbf, rs, col, meanbf);
    k_gemm<1, 0><<<gemm_grid, 256, 0, stream>>>(meanbf, hbf, Bp1, bs[1], hbf,
                                                nullptr, nullptr, nullptr);
    // layer 2 + fused classifier -> out (f32)
    k_aggb<<<agg_grid, 256, 0, stream>>>(hbf, rs, col, meanbf);
    k_gemm<0, 1><<<gemm_grid, 256, 0, stream>>>(meanbf, hbf, Bp2, bs[2], nullptr,
                                                wc, bc, out);
}

// Round 3
// 200.077 us; speedup vs baseline: 2.7260x; 1.2741x over previous
//
#include <hip/hip_runtime.h>

#define N_NODES 50000
#define N_EDGES 800000
#define D 128
#define NGROUPS 3125  // N_NODES / 16

typedef __attribute__((ext_vector_type(8))) short short8;
typedef __attribute__((ext_vector_type(4))) float f32x4;

__device__ __forceinline__ float bits2f(unsigned int u) {
    union { unsigned int u; float f; } c; c.u = u; return c.f;
}
__device__ __forceinline__ unsigned short f2b(float f) {
    union { float f; unsigned int u; } c; c.f = f;
    unsigned int r = c.u + 0x7fffu + ((c.u >> 16) & 1u);
    return (unsigned short)(r >> 16);
}

// ---------------- CSR build ----------------

__global__ void k_degrank(const int* __restrict__ dst, int* __restrict__ deg,
                          int* __restrict__ rank) {
    int e = blockIdx.x * blockDim.x + threadIdx.x;
    if (e < N_EDGES) rank[e] = atomicAdd(&deg[dst[e]], 1);
}

__global__ void k_scan1(const int* __restrict__ deg, int* __restrict__ rs,
                        int* __restrict__ bsum) {
    __shared__ int s[1024];
    int tid = threadIdx.x;
    int i = blockIdx.x * 1024 + tid;
    int v = (i < N_NODES) ? deg[i] : 0;
    s[tid] = v;
    __syncthreads();
    for (int off = 1; off < 1024; off <<= 1) {
        int t = (tid >= off) ? s[tid - off] : 0;
        __syncthreads();
        s[tid] += t;
        __syncthreads();
    }
    if (i < N_NODES) rs[i] = s[tid] - v;
    if (tid == 1023) bsum[blockIdx.x] = s[1023];
}

__global__ void k_scan2(int* __restrict__ bsum, int nb) {
    if (threadIdx.x == 0 && blockIdx.x == 0) {
        int running = 0;
        for (int b = 0; b < nb; ++b) {
            int t = bsum[b];
            bsum[b] = running;
            running += t;
        }
    }
}

__global__ void k_scan3(int* __restrict__ rs, const int* __restrict__ bsum) {
    int i = blockIdx.x * blockDim.x + threadIdx.x;
    if (i < N_NODES) rs[i] += bsum[i >> 10];
    if (i == 0) rs[N_NODES] = N_EDGES;
}

__global__ void k_fill2(const int* __restrict__ src, const int* __restrict__ dst,
                        const int* __restrict__ rs, const int* __restrict__ rank,
                        int* __restrict__ col) {
    int e = blockIdx.x * blockDim.x + threadIdx.x;
    if (e < N_EDGES) col[rs[dst[e]] + rank[e]] = src[e];
}

// ---------------- f32 -> bf16 cast ----------------

__global__ void k_cast(const float* __restrict__ x, unsigned short* __restrict__ xb) {
    int i = blockIdx.x * blockDim.x + threadIdx.x;
    if (i >= (N_NODES * D) / 4) return;
    float4 v = reinterpret_cast<const float4*>(x)[i];
    ushort4 o;
    o.x = f2b(v.x); o.y = f2b(v.y); o.z = f2b(v.z); o.w = f2b(v.w);
    reinterpret_cast<ushort4*>(xb)[i] = o;
}

// ---------------- pack weights into MFMA B-fragment order ----------------
// Bp[layer][kstep][cf][lane][i] = W[kstep*32 + 8*(lane>>4) + i][cf*16 + (lane&15)]
// kstep<4 -> w_nbr, else w_root (k offset -128).

__global__ void k_packw(const float* __restrict__ wn0, const float* __restrict__ wr0,
                        const float* __restrict__ wn1, const float* __restrict__ wr1,
                        const float* __restrict__ wn2, const float* __restrict__ wr2,
                        unsigned short* __restrict__ Bp) {
    int t = blockIdx.x * blockDim.x + threadIdx.x;
    if (t >= 3 * 8 * 8 * 64) return;
    int layer = t >> 12;
    int rem = t & 4095;
    int kstep = rem >> 9;
    int cf = (rem >> 6) & 7;
    int lane = t & 63;
    const float* wns[3] = {wn0, wn1, wn2};
    const float* wrs[3] = {wr0, wr1, wr2};
    int kb = kstep * 32 + (lane >> 4) * 8;
    int colv = cf * 16 + (lane & 15);
    const float* W = (kstep < 4) ? wns[layer] : wrs[layer];
    int koff = (kstep < 4) ? kb : kb - 128;
    unsigned short* dstp = Bp + (((layer * 64 + kstep * 8 + cf) * 64 + lane) << 3);
    #pragma unroll
    for (int i = 0; i < 8; ++i) dstp[i] = f2b(W[(koff + i) * D + colv]);
}

// ---------------- fused: mean-gather + MFMA GEMM (+relu / +cls) ----------
// One wave per 16-row group. Gather phase: each quartet (16 lanes) computes
// means for 4 nodes, 4 neighbor rows in flight (16/wave), writes bf16 mean
// to XOR-swizzled LDS. MFMA phase: A from LDS (mean) / global (h), B packed.

#define ACCUM(v)                                                      \
    acc0 += bits2f((v).x << 16); acc1 += bits2f((v).x & 0xffff0000u); \
    acc2 += bits2f((v).y << 16); acc3 += bits2f((v).y & 0xffff0000u); \
    acc4 += bits2f((v).z << 16); acc5 += bits2f((v).z & 0xffff0000u); \
    acc6 += bits2f((v).w << 16); acc7 += bits2f((v).w & 0xffff0000u);

template <int ACT, int CLS>
__global__ __launch_bounds__(256) void k_fused(
    const unsigned short* __restrict__ Ain, const int* __restrict__ rs,
    const int* __restrict__ col, const unsigned short* __restrict__ Bp,
    const float* __restrict__ bias, unsigned short* __restrict__ outh,
    const float* __restrict__ wc, const float* __restrict__ bc,
    float* __restrict__ outf) {
    __shared__ unsigned short mlds[4][16 * 128];  // 16 KB, per-wave private
    const int wave = threadIdx.x >> 6;
    const int lane = threadIdx.x & 63;
    const int group = blockIdx.x * 4 + wave;
    if (group >= NGROUPS) return;
    const int row0 = group * 16;
    const int q = lane >> 4;     // quartet id
    const int hl = lane & 15;
    const int d8 = hl * 8;       // 8 bf16 (16 B) per lane

    // ---- gather-mean phase ----
    char* myl = (char*)&mlds[wave][0];
    #pragma unroll
    for (int nn = 0; nn < 4; ++nn) {
        int node = row0 + nn * 4 + q;
        int j0 = rs[node], j1 = rs[node + 1];
        float acc0 = 0.f, acc1 = 0.f, acc2 = 0.f, acc3 = 0.f;
        float acc4 = 0.f, acc5 = 0.f, acc6 = 0.f, acc7 = 0.f;
        int j = j0;
        for (; j + 4 <= j1; j += 4) {
            int c0 = col[j], c1 = col[j + 1], c2 = col[j + 2], c3 = col[j + 3];
            uint4 v0 = *(const uint4*)(Ain + (size_t)c0 * D + d8);
            uint4 v1 = *(const uint4*)(Ain + (size_t)c1 * D + d8);
            uint4 v2 = *(const uint4*)(Ain + (size_t)c2 * D + d8);
            uint4 v3 = *(const uint4*)(Ain + (size_t)c3 * D + d8);
            ACCUM(v0); ACCUM(v1); ACCUM(v2); ACCUM(v3);
        }
        for (; j < j1; ++j) {
            int c = col[j];
            uint4 v = *(const uint4*)(Ain + (size_t)c * D + d8);
            ACCUM(v);
        }
        int cnt = j1 - j0;
        float s = 1.0f / (float)(cnt > 0 ? cnt : 1);
        uint4 o;
        o.x = (unsigned int)f2b(acc0 * s) | ((unsigned int)f2b(acc1 * s) << 16);
        o.y = (unsigned int)f2b(acc2 * s) | ((unsigned int)f2b(acc3 * s) << 16);
        o.z = (unsigned int)f2b(acc4 * s) | ((unsigned int)f2b(acc5 * s) << 16);
        o.w = (unsigned int)f2b(acc6 * s) | ((unsigned int)f2b(acc7 * s) << 16);
        int row = nn * 4 + q;
        int boff = (row * 256 + d8 * 2) ^ ((row & 7) << 4);
        *(uint4*)(myl + boff) = o;
    }
    // same-wave LDS RAW: compiler inserts lgkmcnt wait.

    // ---- MFMA phase ----
    f32x4 acc[8];
    #pragma unroll
    for (int i = 0; i < 8; ++i) acc[i] = (f32x4)0.0f;
    const short8* bpv = reinterpret_cast<const short8*>(Bp);
    #pragma unroll
    for (int kstep = 0; kstep < 8; ++kstep) {
        short8 a;
        if (kstep < 4) {
            int boff = (hl * 256 + kstep * 64 + q * 16) ^ ((hl & 7) << 4);
            a = *(const short8*)(myl + boff);
        } else {
            a = *(const short8*)(Ain + (size_t)(row0 + hl) * D +
                                 (kstep - 4) * 32 + q * 8);
        }
        #pragma unroll
        for (int cf = 0; cf < 8; ++cf) {
            short8 b = bpv[(kstep * 8 + cf) * 64 + lane];
            acc[cf] = __builtin_amdgcn_mfma_f32_16x16x32_bf16(a, b, acc[cf], 0, 0, 0);
        }
    }

    // ---- epilogue ----
    int rbase = row0 + q * 4;
    if (CLS) {
        float p0 = 0.f, p1 = 0.f, p2 = 0.f, p3 = 0.f;
        #pragma unroll
        for (int cf = 0; cf < 8; ++cf) {
            int bcol = cf * 16 + hl;
            float bv = bias[bcol];
            float wcv = wc[bcol];
            p0 += (acc[cf][0] + bv) * wcv;
            p1 += (acc[cf][1] + bv) * wcv;
            p2 += (acc[cf][2] + bv) * wcv;
            p3 += (acc[cf][3] + bv) * wcv;
        }
        #pragma unroll
        for (int m = 1; m < 16; m <<= 1) {
            p0 += __shfl_xor(p0, m, 64);
            p1 += __shfl_xor(p1, m, 64);
            p2 += __shfl_xor(p2, m, 64);
            p3 += __shfl_xor(p3, m, 64);
        }
        if (hl == 0) {
            float bcv = bc[0];
            outf[rbase + 0] = p0 + bcv;
            outf[rbase + 1] = p1 + bcv;
            outf[rbase + 2] = p2 + bcv;
            outf[rbase + 3] = p3 + bcv;
        }
    } else {
        #pragma unroll
        for (int cf = 0; cf < 8; ++cf) {
            int bcol = cf * 16 + hl;
            float bv = bias[bcol];
            #pragma unroll
            for (int i = 0; i < 4; ++i) {
                float v = acc[cf][i] + bv;
                if (ACT) v = fmaxf(v, 0.f);
                outh[(size_t)(rbase + i) * D + bcol] = f2b(v);
            }
        }
    }
}

// ---------------- launch ----------------

extern "C" void kernel_launch(void* const* d_in, const int* in_sizes, int n_in,
                              void* d_out, int out_size, void* d_ws,
                              size_t ws_size, hipStream_t stream) {
    const float* x = (const float*)d_in[0];
    const int* ei = (const int*)d_in[1];
    const int* src = ei;
    const int* dst = ei + N_EDGES;
    const float* wn[3] = {(const float*)d_in[2], (const float*)d_in[5],
                          (const float*)d_in[8]};
    const float* wr[3] = {(const float*)d_in[3], (const float*)d_in[6],
                          (const float*)d_in[9]};
    const float* bs[3] = {(const float*)d_in[4], (const float*)d_in[7],
                          (const float*)d_in[10]};
    const float* wc = (const float*)d_in[11];
    const float* bc = (const float*)d_in[12];
    float* out = (float*)d_out;

    char* ws = (char*)d_ws;
    size_t off = 0;
    auto alloc = [&](size_t bytes) -> void* {
        void* p = (void*)(ws + off);
        off += (bytes + 255) & ~(size_t)255;
        return p;
    };
    int* deg = (int*)alloc(N_NODES * 4);
    int* rs = (int*)alloc((N_NODES + 1) * 4);
    int* rank = (int*)alloc(N_EDGES * 4);
    int* bsum = (int*)alloc(64 * 4);
    int* col = (int*)alloc(N_EDGES * 4);
    unsigned short* xbf = (unsigned short*)alloc((size_t)N_NODES * D * 2);
    unsigned short* ha = (unsigned short*)alloc((size_t)N_NODES * D * 2);
    unsigned short* hb = (unsigned short*)alloc((size_t)N_NODES * D * 2);
    unsigned short* Bp = (unsigned short*)alloc(3 * 256 * 128 * 2);

    hipMemsetAsync(deg, 0, N_NODES * 4, stream);

    int nb = (N_NODES + 1023) / 1024;
    k_degrank<<<(N_EDGES + 255) / 256, 256, 0, stream>>>(dst, deg, rank);
    k_scan1<<<nb, 1024, 0, stream>>>(deg, rs, bsum);
    k_scan2<<<1, 64, 0, stream>>>(bsum, nb);
    k_scan3<<<(N_NODES + 255) / 256, 256, 0, stream>>>(rs, bsum);
    k_fill2<<<(N_EDGES + 255) / 256, 256, 0, stream>>>(src, dst, rs, rank, col);

    k_cast<<<(N_NODES * D / 4 + 255) / 256, 256, 0, stream>>>(x, xbf);
    k_packw<<<48, 256, 0, stream>>>(wn[0], wr[0], wn[1], wr[1], wn[2], wr[2], Bp);

    const int fgrid = (NGROUPS + 3) / 4;
    unsigned short* Bp0 = Bp;
    unsigned short* Bp1 = Bp + 256 * 128;
    unsigned short* Bp2 = Bp + 2 * 256 * 128;

    // layer 0: xbf -> ha (relu)
    k_fused<1, 0><<<fgrid, 256, 0, stream>>>(xbf, rs, col, Bp0, bs[0], ha,
                                             nullptr, nullptr, nullptr);
    // layer 1: ha -> hb (relu)
    k_fused<1, 0><<<fgrid, 256, 0, stream>>>(ha, rs, col, Bp1, bs[1], hb,
                                             nullptr, nullptr, nullptr);
    // layer 2 + classifier: hb -> out (f32)
    k_fused<0, 1><<<fgrid, 256, 0, stream>>>(hb, rs, col, Bp2, bs[2], nullptr,
                                             wc, bc, out);
}